// Round 1
// baseline (169.184 us; speedup 1.0000x reference)
//
#include <hip/hip_runtime.h>
#include <hip/hip_bf16.h>

#define LEN 4096
#define BATCH 8
#define DM 512
#define KDIM 1024

typedef __attribute__((ext_vector_type(8))) short bf16x8;
typedef __attribute__((ext_vector_type(4))) float f32x4;

__device__ __forceinline__ short f2bf(float f) {
    union { float f; unsigned u; } v; v.f = f;
    unsigned r = v.u + 0x7FFFu + ((v.u >> 16) & 1u);
    return (short)(r >> 16);
}

__global__ __launch_bounds__(256) void cvt_w_kernel(const float* __restrict__ W,
                                                    short* __restrict__ Wb) {
    int i = (blockIdx.x * 256 + threadIdx.x) * 8;
    f32x4 a = *(const f32x4*)(W + i);
    f32x4 b = *(const f32x4*)(W + i + 4);
    bf16x8 v;
    v[0]=f2bf(a[0]); v[1]=f2bf(a[1]); v[2]=f2bf(a[2]); v[3]=f2bf(a[3]);
    v[4]=f2bf(b[0]); v[5]=f2bf(b[1]); v[6]=f2bf(b[2]); v[7]=f2bf(b[3]);
    *(bf16x8*)(Wb + i) = v;
}

// Newton for y^3/3 + y = x, quadratic convergence from y0 = x.
__device__ __forceinline__ float nonsat(float x) {
    float y = x;
    #pragma unroll
    for (int i = 0; i < 7; ++i) {
        float y2  = y * y;
        float num = __builtin_fmaf(y2 * y, 0.66666667f, x);
        float den = y2 + 1.0f;
        y = num * __builtin_amdgcn_rcpf(den);
    }
    return y;
}

// Block: 32 output rows x 512 cols. 4 waves, each wave owns 128 cols.
// Wave tile: 2 m-tiles x 8 n-tiles of 16x16x32 bf16 MFMA, K-loop 32 steps.
template<int WB>
__global__ __launch_bounds__(256) void fused_fwd(
    const float* __restrict__ x, const float* __restrict__ Wf,
    const short* __restrict__ Wb, const float* __restrict__ bias,
    const float* __restrict__ gamma, const float* __restrict__ beta,
    const float* __restrict__ pe, float* __restrict__ out)
{
    const int tid  = threadIdx.x;
    const int wave = tid >> 6;
    const int lane = tid & 63;
    const int lrow = lane & 15;   // A-row / B-col / C-col within 16-tile
    const int kgrp = lane >> 4;   // k-group of 8
    const int n0   = wave * 128;
    const int m0   = blockIdx.x * 32;

    f32x4 acc[2][8];
    #pragma unroll
    for (int a = 0; a < 2; ++a)
        #pragma unroll
        for (int t = 0; t < 8; ++t)
            acc[a][t] = (f32x4){0.f, 0.f, 0.f, 0.f};

    const int mA[2] = { m0 + lrow, m0 + 16 + lrow };

    for (int ks = 0; ks < 32; ++ks) {
        const int kb = ks * 32 + kgrp * 8;
        bf16x8 afrag[2];
        #pragma unroll
        for (int a = 0; a < 2; ++a) {
            // concat([x, pe]): k < 512 -> x[m][k]; k >= 512 -> pe[m/8][k-512]
            const float* src = (kb < 512)
                ? (x  + (size_t)mA[a] * 512 + kb)
                : (pe + (size_t)(mA[a] >> 3) * 512 + (kb - 512));
            f32x4 lo = *(const f32x4*)src;
            f32x4 hi = *(const f32x4*)(src + 4);
            bf16x8 v;
            v[0]=f2bf(lo[0]); v[1]=f2bf(lo[1]); v[2]=f2bf(lo[2]); v[3]=f2bf(lo[3]);
            v[4]=f2bf(hi[0]); v[5]=f2bf(hi[1]); v[6]=f2bf(hi[2]); v[7]=f2bf(hi[3]);
            afrag[a] = v;
        }
        #pragma unroll
        for (int t = 0; t < 8; ++t) {
            const int n = n0 + t * 16 + lrow;
            bf16x8 bfrag;
            if (WB) {
                bfrag = *(const bf16x8*)(Wb + (size_t)n * KDIM + kb);
            } else {
                const float* wsrc = Wf + (size_t)n * KDIM + kb;
                f32x4 lo = *(const f32x4*)wsrc;
                f32x4 hi = *(const f32x4*)(wsrc + 4);
                bf16x8 v;
                v[0]=f2bf(lo[0]); v[1]=f2bf(lo[1]); v[2]=f2bf(lo[2]); v[3]=f2bf(lo[3]);
                v[4]=f2bf(hi[0]); v[5]=f2bf(hi[1]); v[6]=f2bf(hi[2]); v[7]=f2bf(hi[3]);
                bfrag = v;
            }
            acc[0][t] = __builtin_amdgcn_mfma_f32_16x16x32_bf16(afrag[0], bfrag, acc[0][t], 0, 0, 0);
            acc[1][t] = __builtin_amdgcn_mfma_f32_16x16x32_bf16(afrag[1], bfrag, acc[1][t], 0, 0, 0);
        }
    }

    // ---- epilogue: bias -> LayerNorm -> Newton activation -> store ----
    float bcol[8], gcol[8], ecol[8];
    #pragma unroll
    for (int t = 0; t < 8; ++t) {
        const int n = n0 + t * 16 + lrow;
        bcol[t] = bias[n]; gcol[t] = gamma[n]; ecol[t] = beta[n];
    }
    #pragma unroll
    for (int a = 0; a < 2; ++a)
        #pragma unroll
        for (int t = 0; t < 8; ++t)
            #pragma unroll
            for (int j = 0; j < 4; ++j)
                acc[a][t][j] += bcol[t];

    // Row sums: C/D layout col=lane&15, row=(lane>>4)*4+j.
    // Lanes with equal kgrp (16 of them) hold different cols of the same rows.
    __shared__ float red[4][32][2];
    float sum_[2][4], sq_[2][4];
    #pragma unroll
    for (int a = 0; a < 2; ++a)
        #pragma unroll
        for (int j = 0; j < 4; ++j) {
            float s = 0.f, q = 0.f;
            #pragma unroll
            for (int t = 0; t < 8; ++t) { float v = acc[a][t][j]; s += v; q += v * v; }
            #pragma unroll
            for (int msk = 1; msk <= 8; msk <<= 1) {
                s += __shfl_xor(s, msk, 64);
                q += __shfl_xor(q, msk, 64);
            }
            sum_[a][j] = s; sq_[a][j] = q;
        }
    if (lrow == 0) {
        #pragma unroll
        for (int a = 0; a < 2; ++a)
            #pragma unroll
            for (int j = 0; j < 4; ++j) {
                int r = a * 16 + kgrp * 4 + j;
                red[wave][r][0] = sum_[a][j];
                red[wave][r][1] = sq_[a][j];
            }
    }
    __syncthreads();

    #pragma unroll
    for (int a = 0; a < 2; ++a)
        #pragma unroll
        for (int j = 0; j < 4; ++j) {
            const int r = a * 16 + kgrp * 4 + j;
            float S = red[0][r][0] + red[1][r][0] + red[2][r][0] + red[3][r][0];
            float Q = red[0][r][1] + red[1][r][1] + red[2][r][1] + red[3][r][1];
            float mean = S * (1.0f / 512.0f);
            float var  = Q * (1.0f / 512.0f) - mean * mean;
            float rstd = rsqrtf(var + 1e-5f);
            const int m = m0 + a * 16 + kgrp * 4 + j;
            float* orow = out + (size_t)m * 512;
            #pragma unroll
            for (int t = 0; t < 8; ++t) {
                const int n = n0 + t * 16 + lrow;
                float v = (acc[a][t][j] - mean) * rstd * gcol[t] + ecol[t];
                orow[n] = nonsat(v);
            }
        }
}

extern "C" void kernel_launch(void* const* d_in, const int* in_sizes, int n_in,
                              void* d_out, int out_size, void* d_ws, size_t ws_size,
                              hipStream_t stream) {
    const float* x     = (const float*)d_in[0];
    const float* W     = (const float*)d_in[1];
    const float* bias  = (const float*)d_in[2];
    const float* gamma = (const float*)d_in[3];
    const float* beta  = (const float*)d_in[4];
    const float* pe    = (const float*)d_in[5];
    float* out = (float*)d_out;

    const int m_blocks = (LEN * BATCH) / 32;  // 1024

    if (ws_size >= (size_t)(DM * KDIM * sizeof(short))) {
        short* Wb = (short*)d_ws;
        cvt_w_kernel<<<dim3((DM * KDIM) / (256 * 8)), dim3(256), 0, stream>>>(W, Wb);
        fused_fwd<1><<<dim3(m_blocks), dim3(256), 0, stream>>>(x, W, Wb, bias, gamma, beta, pe, out);
    } else {
        fused_fwd<0><<<dim3(m_blocks), dim3(256), 0, stream>>>(x, W, nullptr, bias, gamma, beta, pe, out);
    }
}

// Round 2
// 92.012 us; speedup vs baseline: 1.8387x; 1.8387x over previous
//
#include <hip/hip_runtime.h>
#include <hip/hip_bf16.h>

#define SEQL 4096
#define NBATCH 8
#define MROWS (SEQL*NBATCH)
#define DMODEL 512
#define KFULL 1024

typedef __attribute__((ext_vector_type(8))) short bf16x8;
typedef __attribute__((ext_vector_type(4))) short s16x4;
typedef __attribute__((ext_vector_type(2))) short s16x2;
typedef __attribute__((ext_vector_type(4))) float f32x4;
typedef __attribute__((ext_vector_type(2))) float f32x2;

__device__ __forceinline__ short f2bf(float f) {
    union { float f; unsigned u; } v; v.f = f;
    unsigned r = v.u + 0x7FFFu + ((v.u >> 16) & 1u);
    return (short)(r >> 16);
}

// Newton for y^3/3 + y = x (quadratic convergence; 6 iters -> tail err ~1e-3)
__device__ __forceinline__ float nonsat(float x) {
    float y = x;
    #pragma unroll
    for (int i = 0; i < 6; ++i) {
        float y2  = y * y;
        float num = __builtin_fmaf(y2 * y, 0.66666667f, x);
        y = num * __builtin_amdgcn_rcpf(y2 + 1.0f);
    }
    return y;
}

// W (512x1024 f32 row-major [n][k]) -> fragment-tiled bf16.
// frag f = (k/32)*32 + (n/16); hw lane = ((k/8)&3)*16 + (n&15); elems k..k+7.
// Wbf[f*512 + lane*8 + e] = bf16(W[n][k+e])  -> a wave's B-frag load is 1KB contiguous.
__global__ __launch_bounds__(256) void cvt_w(const float* __restrict__ W,
                                             short* __restrict__ Wbf) {
    int t8 = blockIdx.x * 256 + threadIdx.x;
    int n = t8 >> 7;            // 128 chunks of 8 per row
    int k = (t8 & 127) << 3;
    f32x4 lo = *(const f32x4*)(W + (size_t)n * KFULL + k);
    f32x4 hi = *(const f32x4*)(W + (size_t)n * KFULL + k + 4);
    bf16x8 v;
    v[0]=f2bf(lo[0]); v[1]=f2bf(lo[1]); v[2]=f2bf(lo[2]); v[3]=f2bf(lo[3]);
    v[4]=f2bf(hi[0]); v[5]=f2bf(hi[1]); v[6]=f2bf(hi[2]); v[7]=f2bf(hi[3]);
    int f    = (k >> 5) * 32 + (n >> 4);
    int lane = ((k >> 3) & 3) * 16 + (n & 15);
    *(bf16x8*)(Wbf + (size_t)f * 512 + lane * 8) = v;
}

// P[l][n] = sum_k pe[l][k] * W[n][512+k] + bias[n]   (4096 x 512, fp32)
// Block: 16 rows x 512 cols, 4 waves (each 128 cols, 8 n-frags). K=512, BK=32.
__global__ __launch_bounds__(256) void pe_gemm(const float* __restrict__ pe,
                                               const short* __restrict__ Wbf,
                                               const float* __restrict__ bias,
                                               float* __restrict__ P) {
    __shared__ short As[16 * 32];
    const int tid  = threadIdx.x;
    const int wid  = tid >> 6;
    const int lane = tid & 63;
    const int lrow = lane & 15;
    const int kgrp = lane >> 4;
    const int l0   = blockIdx.x * 16;

    f32x4 acc[8];
    #pragma unroll
    for (int t = 0; t < 8; ++t) acc[t] = (f32x4){0.f, 0.f, 0.f, 0.f};

    const int ar = tid >> 4;            // row 0..15
    const int ak = (tid & 15) << 1;     // 2 elems per thread
    const float* psrc = pe + (size_t)(l0 + ar) * DMODEL + ak;

    for (int ks = 0; ks < 16; ++ks) {
        f32x2 pv = *(const f32x2*)(psrc + ks * 32);
        s16x2 w2; w2[0] = f2bf(pv[0]); w2[1] = f2bf(pv[1]);
        *(s16x2*)(As + ar * 32 + ak) = w2;
        __syncthreads();
        bf16x8 af = *(const bf16x8*)(As + lrow * 32 + kgrp * 8);
        const short* bp = Wbf + (size_t)((16 + ks) * 32 + wid * 8) * 512 + lane * 8;
        #pragma unroll
        for (int t = 0; t < 8; ++t) {
            bf16x8 bf = *(const bf16x8*)(bp + t * 512);
            acc[t] = __builtin_amdgcn_mfma_f32_16x16x32_bf16(af, bf, acc[t], 0, 0, 0);
        }
        __syncthreads();
    }

    float bcol[8];
    #pragma unroll
    for (int t = 0; t < 8; ++t) bcol[t] = bias[wid * 128 + t * 16 + lrow];
    #pragma unroll
    for (int j = 0; j < 4; ++j) {
        int l = l0 + kgrp * 4 + j;
        float* prow = P + (size_t)l * DMODEL + wid * 128 + lrow;
        #pragma unroll
        for (int t = 0; t < 8; ++t) prow[t * 16] = acc[t][j] + bcol[t];
    }
}

// Main: out = nonsat(LN(x @ W1^T + P[l]))
// Block: 64 rows x 512 cols, 8 waves (2 m-waves x 4 n-waves), K=512, BK=32.
// B-frags direct from fragment-tiled Wbf (L2-resident); A staged in LDS (fp32->bf16).
__global__ __launch_bounds__(512, 4) void main_fused(
    const float* __restrict__ x, const short* __restrict__ Wbf,
    const float* __restrict__ P, const float* __restrict__ gamma,
    const float* __restrict__ beta, float* __restrict__ out)
{
    __shared__ short As[64 * 32];
    __shared__ float red[8][32][2];

    const int tid  = threadIdx.x;
    const int wid  = tid >> 6;
    const int lane = tid & 63;
    const int lrow = lane & 15;
    const int kgrp = lane >> 4;
    const int wm   = wid >> 2;
    const int wn   = wid & 3;
    const int m0   = blockIdx.x * 64;

    f32x4 acc[2][8];
    #pragma unroll
    for (int a = 0; a < 2; ++a)
        #pragma unroll
        for (int t = 0; t < 8; ++t)
            acc[a][t] = (f32x4){0.f, 0.f, 0.f, 0.f};

    // A staging: thread -> (row = tid/8, 4 k-elems at (tid&7)*4)
    const int ar = tid >> 3;
    const int ak = (tid & 7) << 2;
    const float* xsrc = x + (size_t)(m0 + ar) * DMODEL + ak;

    f32x4 xv = *(const f32x4*)xsrc;   // k-step 0
    for (int ks = 0; ks < 16; ++ks) {
        s16x4 w4;
        w4[0] = f2bf(xv[0]); w4[1] = f2bf(xv[1]);
        w4[2] = f2bf(xv[2]); w4[3] = f2bf(xv[3]);
        *(s16x4*)(As + ar * 32 + ak) = w4;          // ds_write_b64
        __syncthreads();
        if (ks < 15) xv = *(const f32x4*)(xsrc + (ks + 1) * 32);  // issue early

        bf16x8 af0 = *(const bf16x8*)(As + (wm * 32 + lrow) * 32 + kgrp * 8);
        bf16x8 af1 = *(const bf16x8*)(As + (wm * 32 + 16 + lrow) * 32 + kgrp * 8);
        const short* bp = Wbf + (size_t)(ks * 32 + wn * 8) * 512 + lane * 8;
        #pragma unroll
        for (int t = 0; t < 8; ++t) {
            bf16x8 bf = *(const bf16x8*)(bp + t * 512);
            acc[0][t] = __builtin_amdgcn_mfma_f32_16x16x32_bf16(af0, bf, acc[0][t], 0, 0, 0);
            acc[1][t] = __builtin_amdgcn_mfma_f32_16x16x32_bf16(af1, bf, acc[1][t], 0, 0, 0);
        }
        __syncthreads();
    }

    // ---- epilogue: +P -> LayerNorm -> nonsat -> store ----
    float gcol[8], ecol[8];
    #pragma unroll
    for (int t = 0; t < 8; ++t) {
        int n = wn * 128 + t * 16 + lrow;
        gcol[t] = gamma[n]; ecol[t] = beta[n];
    }
    #pragma unroll
    for (int a = 0; a < 2; ++a)
        #pragma unroll
        for (int j = 0; j < 4; ++j) {
            int m = m0 + wm * 32 + a * 16 + kgrp * 4 + j;
            const float* prow = P + (size_t)(m >> 3) * DMODEL + wn * 128 + lrow;
            #pragma unroll
            for (int t = 0; t < 8; ++t)
                acc[a][t][j] += prow[t * 16];
        }

    float sm[2][4], sq[2][4];
    #pragma unroll
    for (int a = 0; a < 2; ++a)
        #pragma unroll
        for (int j = 0; j < 4; ++j) {
            float s = 0.f, q = 0.f;
            #pragma unroll
            for (int t = 0; t < 8; ++t) {
                float v = acc[a][t][j];
                s += v; q = __builtin_fmaf(v, v, q);
            }
            #pragma unroll
            for (int msk = 1; msk <= 8; msk <<= 1) {
                s += __shfl_xor(s, msk, 64);
                q += __shfl_xor(q, msk, 64);
            }
            sm[a][j] = s; sq[a][j] = q;
        }
    if (lrow == 0) {
        #pragma unroll
        for (int a = 0; a < 2; ++a)
            #pragma unroll
            for (int j = 0; j < 4; ++j) {
                int rl = a * 16 + kgrp * 4 + j;
                red[wid][rl][0] = sm[a][j];
                red[wid][rl][1] = sq[a][j];
            }
    }
    __syncthreads();

    #pragma unroll
    for (int a = 0; a < 2; ++a)
        #pragma unroll
        for (int j = 0; j < 4; ++j) {
            int rl = a * 16 + kgrp * 4 + j;
            int wb = wm * 4;
            float S = red[wb][rl][0] + red[wb+1][rl][0] + red[wb+2][rl][0] + red[wb+3][rl][0];
            float Q = red[wb][rl][1] + red[wb+1][rl][1] + red[wb+2][rl][1] + red[wb+3][rl][1];
            float mean = S * (1.0f / 512.0f);
            float var  = Q * (1.0f / 512.0f) - mean * mean;
            float rstd = rsqrtf(var + 1e-5f);
            int m = m0 + wm * 32 + rl;
            float* orow = out + (size_t)m * DMODEL + wn * 128 + lrow;
            #pragma unroll
            for (int t = 0; t < 8; ++t) {
                float v = (acc[a][t][j] - mean) * rstd * gcol[t] + ecol[t];
                orow[t * 16] = nonsat(v);
            }
        }
}

// ---------- fallback (no workspace): round-1 direct kernel ----------
__global__ __launch_bounds__(256) void fallback_fwd(
    const float* __restrict__ x, const float* __restrict__ Wf,
    const float* __restrict__ bias, const float* __restrict__ gamma,
    const float* __restrict__ beta, const float* __restrict__ pe,
    float* __restrict__ out)
{
    const int tid  = threadIdx.x;
    const int wave = tid >> 6;
    const int lane = tid & 63;
    const int lrow = lane & 15;
    const int kgrp = lane >> 4;
    const int n0   = wave * 128;
    const int m0   = blockIdx.x * 32;

    f32x4 acc[2][8];
    #pragma unroll
    for (int a = 0; a < 2; ++a)
        #pragma unroll
        for (int t = 0; t < 8; ++t)
            acc[a][t] = (f32x4){0.f, 0.f, 0.f, 0.f};

    const int mA[2] = { m0 + lrow, m0 + 16 + lrow };
    for (int ks = 0; ks < 32; ++ks) {
        const int kb = ks * 32 + kgrp * 8;
        bf16x8 afrag[2];
        #pragma unroll
        for (int a = 0; a < 2; ++a) {
            const float* src = (kb < 512)
                ? (x  + (size_t)mA[a] * 512 + kb)
                : (pe + (size_t)(mA[a] >> 3) * 512 + (kb - 512));
            f32x4 lo = *(const f32x4*)src;
            f32x4 hi = *(const f32x4*)(src + 4);
            bf16x8 v;
            v[0]=f2bf(lo[0]); v[1]=f2bf(lo[1]); v[2]=f2bf(lo[2]); v[3]=f2bf(lo[3]);
            v[4]=f2bf(hi[0]); v[5]=f2bf(hi[1]); v[6]=f2bf(hi[2]); v[7]=f2bf(hi[3]);
            afrag[a] = v;
        }
        #pragma unroll
        for (int t = 0; t < 8; ++t) {
            const int n = n0 + t * 16 + lrow;
            const float* wsrc = Wf + (size_t)n * KFULL + kb;
            f32x4 lo = *(const f32x4*)wsrc;
            f32x4 hi = *(const f32x4*)(wsrc + 4);
            bf16x8 bfr;
            bfr[0]=f2bf(lo[0]); bfr[1]=f2bf(lo[1]); bfr[2]=f2bf(lo[2]); bfr[3]=f2bf(lo[3]);
            bfr[4]=f2bf(hi[0]); bfr[5]=f2bf(hi[1]); bfr[6]=f2bf(hi[2]); bfr[7]=f2bf(hi[3]);
            acc[0][t] = __builtin_amdgcn_mfma_f32_16x16x32_bf16(afrag[0], bfr, acc[0][t], 0, 0, 0);
            acc[1][t] = __builtin_amdgcn_mfma_f32_16x16x32_bf16(afrag[1], bfr, acc[1][t], 0, 0, 0);
        }
    }
    __shared__ float red[4][32][2];
    float bcol[8], gcol[8], ecol[8];
    #pragma unroll
    for (int t = 0; t < 8; ++t) {
        const int n = n0 + t * 16 + lrow;
        bcol[t] = bias[n]; gcol[t] = gamma[n]; ecol[t] = beta[n];
    }
    #pragma unroll
    for (int a = 0; a < 2; ++a)
        #pragma unroll
        for (int t = 0; t < 8; ++t)
            #pragma unroll
            for (int j = 0; j < 4; ++j)
                acc[a][t][j] += bcol[t];
    float sm[2][4], sq[2][4];
    #pragma unroll
    for (int a = 0; a < 2; ++a)
        #pragma unroll
        for (int j = 0; j < 4; ++j) {
            float s = 0.f, q = 0.f;
            #pragma unroll
            for (int t = 0; t < 8; ++t) { float v = acc[a][t][j]; s += v; q += v * v; }
            #pragma unroll
            for (int msk = 1; msk <= 8; msk <<= 1) {
                s += __shfl_xor(s, msk, 64);
                q += __shfl_xor(q, msk, 64);
            }
            sm[a][j] = s; sq[a][j] = q;
        }
    if (lrow == 0) {
        #pragma unroll
        for (int a = 0; a < 2; ++a)
            #pragma unroll
            for (int j = 0; j < 4; ++j) {
                int r = a * 16 + kgrp * 4 + j;
                red[wave][r][0] = sm[a][j];
                red[wave][r][1] = sq[a][j];
            }
    }
    __syncthreads();
    #pragma unroll
    for (int a = 0; a < 2; ++a)
        #pragma unroll
        for (int j = 0; j < 4; ++j) {
            const int r = a * 16 + kgrp * 4 + j;
            float S = red[0][r][0] + red[1][r][0] + red[2][r][0] + red[3][r][0];
            float Q = red[0][r][1] + red[1][r][1] + red[2][r][1] + red[3][r][1];
            float mean = S * (1.0f / 512.0f);
            float var  = Q * (1.0f / 512.0f) - mean * mean;
            float rstd = rsqrtf(var + 1e-5f);
            const int m = m0 + a * 16 + kgrp * 4 + j;
            float* orow = out + (size_t)m * 512;
            #pragma unroll
            for (int t = 0; t < 8; ++t) {
                const int n = n0 + t * 16 + lrow;
                float v = (acc[a][t][j] - mean) * rstd * gcol[t] + ecol[t];
                orow[n] = nonsat(v);
            }
        }
}

extern "C" void kernel_launch(void* const* d_in, const int* in_sizes, int n_in,
                              void* d_out, int out_size, void* d_ws, size_t ws_size,
                              hipStream_t stream) {
    const float* x     = (const float*)d_in[0];
    const float* W     = (const float*)d_in[1];
    const float* bias  = (const float*)d_in[2];
    const float* gamma = (const float*)d_in[3];
    const float* beta  = (const float*)d_in[4];
    const float* pe    = (const float*)d_in[5];
    float* out = (float*)d_out;

    const size_t WBF_BYTES = (size_t)KFULL * DMODEL * sizeof(short);   // 1 MB
    const size_t P_BYTES   = (size_t)SEQL * DMODEL * sizeof(float);    // 8 MB

    if (ws_size >= WBF_BYTES + P_BYTES) {
        short* Wbf = (short*)d_ws;
        float* P   = (float*)((char*)d_ws + WBF_BYTES);
        cvt_w<<<dim3((DMODEL * KFULL) / (256 * 8)), dim3(256), 0, stream>>>(W, Wbf);
        pe_gemm<<<dim3(SEQL / 16), dim3(256), 0, stream>>>(pe, Wbf, bias, P);
        main_fused<<<dim3(MROWS / 64), dim3(512), 0, stream>>>(x, Wbf, P, gamma, beta, out);
    } else {
        fallback_fwd<<<dim3(MROWS / 32), dim3(256), 0, stream>>>(x, W, bias, gamma, beta, pe, out);
    }
}

// Round 3
// 88.184 us; speedup vs baseline: 1.9185x; 1.0434x over previous
//
#include <hip/hip_runtime.h>
#include <hip/hip_bf16.h>

#define SEQL 4096
#define NBATCH 8
#define MROWS (SEQL*NBATCH)
#define DMODEL 512
#define KFULL 1024

typedef __attribute__((ext_vector_type(8))) short bf16x8;
typedef __attribute__((ext_vector_type(4))) short s16x4;
typedef __attribute__((ext_vector_type(4))) float f32x4;

__device__ __forceinline__ short f2bf(float f) {
    union { float f; unsigned u; } v; v.f = f;
    unsigned r = v.u + 0x7FFFu + ((v.u >> 16) & 1u);
    return (short)(r >> 16);
}

// Newton for y^3/3 + y = x
__device__ __forceinline__ float nonsat(float x) {
    float y = x;
    #pragma unroll
    for (int i = 0; i < 6; ++i) {
        float y2  = y * y;
        float num = __builtin_fmaf(y2 * y, 0.66666667f, x);
        y = num * __builtin_amdgcn_rcpf(y2 + 1.0f);
    }
    return y;
}

// W (512x1024 f32 [n][k]) -> fragment-tiled bf16:
// frag f = (k/32)*32 + (n/16); lane = ((k/8)&3)*16 + (n&15); elems k..k+7.
__global__ __launch_bounds__(256) void cvt_w(const float* __restrict__ W,
                                             short* __restrict__ Wbf) {
    int t8 = blockIdx.x * 256 + threadIdx.x;
    int n = t8 >> 7;
    int k = (t8 & 127) << 3;
    f32x4 lo = *(const f32x4*)(W + (size_t)n * KFULL + k);
    f32x4 hi = *(const f32x4*)(W + (size_t)n * KFULL + k + 4);
    bf16x8 v;
    v[0]=f2bf(lo[0]); v[1]=f2bf(lo[1]); v[2]=f2bf(lo[2]); v[3]=f2bf(lo[3]);
    v[4]=f2bf(hi[0]); v[5]=f2bf(hi[1]); v[6]=f2bf(hi[2]); v[7]=f2bf(hi[3]);
    int f    = (k >> 5) * 32 + (n >> 4);
    int lane = ((k >> 3) & 3) * 16 + (n & 15);
    *(bf16x8*)(Wbf + (size_t)f * 512 + lane * 8) = v;
}

// ---- shared GEMM skeleton: 32 rows x 512 cols per block, 4 waves, BK=64,
// ---- double-buffered swizzled LDS A-tile, B direct from fragment-tiled Wbf.

// pe_gemm: Pv[(l*16+lrow)*32 + wn*8 + t] = (pe @ W2^T)[l][n] + bias[n]
__global__ __launch_bounds__(256, 3) void pe_gemm(const float* __restrict__ pe,
                                                  const short* __restrict__ Wbf,
                                                  const float* __restrict__ bias,
                                                  float* __restrict__ Pv) {
    __shared__ short As[2][32 * 64];
    const int tid  = threadIdx.x;
    const int wn   = tid >> 6;
    const int lane = tid & 63;
    const int lrow = lane & 15;
    const int kgrp = lane >> 4;
    const int l0   = blockIdx.x * 32;

    const int ar = tid >> 3;
    const int kc = tid & 7;
    const int sidx = (ar * 64 + kc * 8) ^ ((ar & 7) << 3);
    const float* xp = pe + (size_t)(l0 + ar) * DMODEL + kc * 8;

    f32x4 acc[2][8];
    #pragma unroll
    for (int a = 0; a < 2; ++a)
        #pragma unroll
        for (int t = 0; t < 8; ++t) acc[a][t] = (f32x4){0.f,0.f,0.f,0.f};

    f32x4 xl[2], xh[2];
    xl[0] = *(const f32x4*)xp; xh[0] = *(const f32x4*)(xp + 4);
    {
        bf16x8 v;
        v[0]=f2bf(xl[0][0]); v[1]=f2bf(xl[0][1]); v[2]=f2bf(xl[0][2]); v[3]=f2bf(xl[0][3]);
        v[4]=f2bf(xh[0][0]); v[5]=f2bf(xh[0][1]); v[6]=f2bf(xh[0][2]); v[7]=f2bf(xh[0][3]);
        *(bf16x8*)&As[0][sidx] = v;
    }
    xl[1] = *(const f32x4*)(xp + 64); xh[1] = *(const f32x4*)(xp + 68);
    __syncthreads();

    #pragma unroll
    for (int ks = 0; ks < 8; ++ks) {
        const int cur = ks & 1;
        if (ks < 7) {
            bf16x8 v;
            v[0]=f2bf(xl[cur^1][0]); v[1]=f2bf(xl[cur^1][1]); v[2]=f2bf(xl[cur^1][2]); v[3]=f2bf(xl[cur^1][3]);
            v[4]=f2bf(xh[cur^1][0]); v[5]=f2bf(xh[cur^1][1]); v[6]=f2bf(xh[cur^1][2]); v[7]=f2bf(xh[cur^1][3]);
            *(bf16x8*)&As[cur ^ 1][sidx] = v;
        }
        if (ks < 6) {
            xl[cur] = *(const f32x4*)(xp + (ks + 2) * 64);
            xh[cur] = *(const f32x4*)(xp + (ks + 2) * 64 + 4);
        }
        #pragma unroll
        for (int ksub = 0; ksub < 2; ++ksub) {
            bf16x8 af[2];
            #pragma unroll
            for (int a = 0; a < 2; ++a) {
                int idx = ((a * 16 + lrow) * 64 + ksub * 32 + kgrp * 8) ^ ((lrow & 7) << 3);
                af[a] = *(const bf16x8*)&As[cur][idx];
            }
            const short* bp = Wbf + (size_t)((16 + ks * 2 + ksub) * 32 + wn * 8) * 512 + lane * 8;
            __builtin_amdgcn_s_setprio(1);
            #pragma unroll
            for (int t = 0; t < 8; ++t) {
                bf16x8 bf = *(const bf16x8*)(bp + (size_t)t * 512);
                acc[0][t] = __builtin_amdgcn_mfma_f32_16x16x32_bf16(af[0], bf, acc[0][t], 0, 0, 0);
                acc[1][t] = __builtin_amdgcn_mfma_f32_16x16x32_bf16(af[1], bf, acc[1][t], 0, 0, 0);
            }
            __builtin_amdgcn_s_setprio(0);
        }
        __syncthreads();
    }

    float bcol[8];
    #pragma unroll
    for (int t = 0; t < 8; ++t) bcol[t] = bias[wn * 128 + t * 16 + lrow];
    #pragma unroll
    for (int a = 0; a < 2; ++a)
        #pragma unroll
        for (int j = 0; j < 4; ++j) {
            int l = l0 + a * 16 + kgrp * 4 + j;
            float* pv = Pv + ((size_t)l * 16 + lrow) * 32 + wn * 8;
            f32x4 v0, v1;
            #pragma unroll
            for (int t = 0; t < 4; ++t) v0[t] = acc[a][t][j] + bcol[t];
            #pragma unroll
            for (int t = 0; t < 4; ++t) v1[t] = acc[a][t + 4][j] + bcol[t + 4];
            *(f32x4*)pv = v0;
            *(f32x4*)(pv + 4) = v1;
        }
}

// main: out = nonsat(LN(x @ W1^T + Pv[l]))
__global__ __launch_bounds__(256, 3) void main_fused(
    const float* __restrict__ x, const short* __restrict__ Wbf,
    const float* __restrict__ Pv, const float* __restrict__ gamma,
    const float* __restrict__ beta, float* __restrict__ out)
{
    __shared__ short As[2][32 * 64];
    __shared__ float red[4][32][2];

    const int tid  = threadIdx.x;
    const int wn   = tid >> 6;
    const int lane = tid & 63;
    const int lrow = lane & 15;
    const int kgrp = lane >> 4;
    const int m0   = blockIdx.x * 32;

    const int ar = tid >> 3;
    const int kc = tid & 7;
    const int sidx = (ar * 64 + kc * 8) ^ ((ar & 7) << 3);
    const float* xp = x + (size_t)(m0 + ar) * DMODEL + kc * 8;

    f32x4 acc[2][8];
    #pragma unroll
    for (int a = 0; a < 2; ++a)
        #pragma unroll
        for (int t = 0; t < 8; ++t) acc[a][t] = (f32x4){0.f,0.f,0.f,0.f};

    f32x4 xl[2], xh[2];
    xl[0] = *(const f32x4*)xp; xh[0] = *(const f32x4*)(xp + 4);
    {
        bf16x8 v;
        v[0]=f2bf(xl[0][0]); v[1]=f2bf(xl[0][1]); v[2]=f2bf(xl[0][2]); v[3]=f2bf(xl[0][3]);
        v[4]=f2bf(xh[0][0]); v[5]=f2bf(xh[0][1]); v[6]=f2bf(xh[0][2]); v[7]=f2bf(xh[0][3]);
        *(bf16x8*)&As[0][sidx] = v;
    }
    xl[1] = *(const f32x4*)(xp + 64); xh[1] = *(const f32x4*)(xp + 68);
    __syncthreads();

    #pragma unroll
    for (int ks = 0; ks < 8; ++ks) {
        const int cur = ks & 1;
        if (ks < 7) {
            bf16x8 v;
            v[0]=f2bf(xl[cur^1][0]); v[1]=f2bf(xl[cur^1][1]); v[2]=f2bf(xl[cur^1][2]); v[3]=f2bf(xl[cur^1][3]);
            v[4]=f2bf(xh[cur^1][0]); v[5]=f2bf(xh[cur^1][1]); v[6]=f2bf(xh[cur^1][2]); v[7]=f2bf(xh[cur^1][3]);
            *(bf16x8*)&As[cur ^ 1][sidx] = v;
        }
        if (ks < 6) {
            xl[cur] = *(const f32x4*)(xp + (ks + 2) * 64);
            xh[cur] = *(const f32x4*)(xp + (ks + 2) * 64 + 4);
        }
        #pragma unroll
        for (int ksub = 0; ksub < 2; ++ksub) {
            bf16x8 af[2];
            #pragma unroll
            for (int a = 0; a < 2; ++a) {
                int idx = ((a * 16 + lrow) * 64 + ksub * 32 + kgrp * 8) ^ ((lrow & 7) << 3);
                af[a] = *(const bf16x8*)&As[cur][idx];
            }
            const short* bp = Wbf + (size_t)((ks * 2 + ksub) * 32 + wn * 8) * 512 + lane * 8;
            __builtin_amdgcn_s_setprio(1);
            #pragma unroll
            for (int t = 0; t < 8; ++t) {
                bf16x8 bf = *(const bf16x8*)(bp + (size_t)t * 512);
                acc[0][t] = __builtin_amdgcn_mfma_f32_16x16x32_bf16(af[0], bf, acc[0][t], 0, 0, 0);
                acc[1][t] = __builtin_amdgcn_mfma_f32_16x16x32_bf16(af[1], bf, acc[1][t], 0, 0, 0);
            }
            __builtin_amdgcn_s_setprio(0);
        }
        __syncthreads();
    }

    // ---- epilogue: +P -> LayerNorm -> nonsat -> store ----
    float gcol[8], ecol[8];
    #pragma unroll
    for (int t = 0; t < 8; ++t) {
        int n = wn * 128 + t * 16 + lrow;
        gcol[t] = gamma[n]; ecol[t] = beta[n];
    }
    #pragma unroll
    for (int a = 0; a < 2; ++a)
        #pragma unroll
        for (int j = 0; j < 4; ++j) {
            int m = m0 + a * 16 + kgrp * 4 + j;
            int l = m >> 3;
            const float* pv = Pv + ((size_t)l * 16 + lrow) * 32 + wn * 8;
            f32x4 p0 = *(const f32x4*)pv;
            f32x4 p1 = *(const f32x4*)(pv + 4);
            #pragma unroll
            for (int t = 0; t < 4; ++t) acc[a][t][j]     += p0[t];
            #pragma unroll
            for (int t = 0; t < 4; ++t) acc[a][t + 4][j] += p1[t];
        }

    float sm[2][4], sq[2][4];
    #pragma unroll
    for (int a = 0; a < 2; ++a)
        #pragma unroll
        for (int j = 0; j < 4; ++j) {
            float s = 0.f, q = 0.f;
            #pragma unroll
            for (int t = 0; t < 8; ++t) {
                float v = acc[a][t][j];
                s += v; q = __builtin_fmaf(v, v, q);
            }
            #pragma unroll
            for (int msk = 1; msk <= 8; msk <<= 1) {
                s += __shfl_xor(s, msk, 64);
                q += __shfl_xor(q, msk, 64);
            }
            sm[a][j] = s; sq[a][j] = q;
        }
    if (lrow == 0) {
        #pragma unroll
        for (int a = 0; a < 2; ++a)
            #pragma unroll
            for (int j = 0; j < 4; ++j) {
                int rl = a * 16 + kgrp * 4 + j;
                red[wn][rl][0] = sm[a][j];
                red[wn][rl][1] = sq[a][j];
            }
    }
    __syncthreads();

    #pragma unroll
    for (int a = 0; a < 2; ++a)
        #pragma unroll
        for (int j = 0; j < 4; ++j) {
            int rl = a * 16 + kgrp * 4 + j;
            float S = red[0][rl][0] + red[1][rl][0] + red[2][rl][0] + red[3][rl][0];
            float Q = red[0][rl][1] + red[1][rl][1] + red[2][rl][1] + red[3][rl][1];
            float mean = S * (1.0f / 512.0f);
            float var  = Q * (1.0f / 512.0f) - mean * mean;
            float rstd = rsqrtf(var + 1e-5f);
            int m = m0 + rl;
            float* orow = out + (size_t)m * DMODEL + wn * 128 + lrow;
            #pragma unroll
            for (int t = 0; t < 8; ++t) {
                float v = (acc[a][t][j] - mean) * rstd * gcol[t] + ecol[t];
                orow[t * 16] = nonsat(v);
            }
        }
}

// ---------- fallback (no workspace) ----------
__global__ __launch_bounds__(256) void fallback_fwd(
    const float* __restrict__ x, const float* __restrict__ Wf,
    const float* __restrict__ bias, const float* __restrict__ gamma,
    const float* __restrict__ beta, const float* __restrict__ pe,
    float* __restrict__ out)
{
    const int tid  = threadIdx.x;
    const int wave = tid >> 6;
    const int lane = tid & 63;
    const int lrow = lane & 15;
    const int kgrp = lane >> 4;
    const int n0   = wave * 128;
    const int m0   = blockIdx.x * 32;

    f32x4 acc[2][8];
    #pragma unroll
    for (int a = 0; a < 2; ++a)
        #pragma unroll
        for (int t = 0; t < 8; ++t) acc[a][t] = (f32x4){0.f,0.f,0.f,0.f};

    const int mA[2] = { m0 + lrow, m0 + 16 + lrow };
    for (int ks = 0; ks < 32; ++ks) {
        const int kb = ks * 32 + kgrp * 8;
        bf16x8 afrag[2];
        #pragma unroll
        for (int a = 0; a < 2; ++a) {
            const float* src = (kb < 512)
                ? (x  + (size_t)mA[a] * 512 + kb)
                : (pe + (size_t)(mA[a] >> 3) * 512 + (kb - 512));
            f32x4 lo = *(const f32x4*)src;
            f32x4 hi = *(const f32x4*)(src + 4);
            bf16x8 v;
            v[0]=f2bf(lo[0]); v[1]=f2bf(lo[1]); v[2]=f2bf(lo[2]); v[3]=f2bf(lo[3]);
            v[4]=f2bf(hi[0]); v[5]=f2bf(hi[1]); v[6]=f2bf(hi[2]); v[7]=f2bf(hi[3]);
            afrag[a] = v;
        }
        #pragma unroll
        for (int t = 0; t < 8; ++t) {
            const int n = n0 + t * 16 + lrow;
            const float* wsrc = Wf + (size_t)n * KFULL + kb;
            f32x4 lo = *(const f32x4*)wsrc;
            f32x4 hi = *(const f32x4*)(wsrc + 4);
            bf16x8 bfr;
            bfr[0]=f2bf(lo[0]); bfr[1]=f2bf(lo[1]); bfr[2]=f2bf(lo[2]); bfr[3]=f2bf(lo[3]);
            bfr[4]=f2bf(hi[0]); bfr[5]=f2bf(hi[1]); bfr[6]=f2bf(hi[2]); bfr[7]=f2bf(hi[3]);
            acc[0][t] = __builtin_amdgcn_mfma_f32_16x16x32_bf16(afrag[0], bfr, acc[0][t], 0, 0, 0);
            acc[1][t] = __builtin_amdgcn_mfma_f32_16x16x32_bf16(afrag[1], bfr, acc[1][t], 0, 0, 0);
        }
    }
    __shared__ float red[4][32][2];
    float bcol[8], gcol[8], ecol[8];
    #pragma unroll
    for (int t = 0; t < 8; ++t) {
        const int n = n0 + t * 16 + lrow;
        bcol[t] = bias[n]; gcol[t] = gamma[n]; ecol[t] = beta[n];
    }
    #pragma unroll
    for (int a = 0; a < 2; ++a)
        #pragma unroll
        for (int t = 0; t < 8; ++t)
            #pragma unroll
            for (int j = 0; j < 4; ++j) acc[a][t][j] += bcol[t];
    float sm[2][4], sq[2][4];
    #pragma unroll
    for (int a = 0; a < 2; ++a)
        #pragma unroll
        for (int j = 0; j < 4; ++j) {
            float s = 0.f, q = 0.f;
            #pragma unroll
            for (int t = 0; t < 8; ++t) { float v = acc[a][t][j]; s += v; q += v * v; }
            #pragma unroll
            for (int msk = 1; msk <= 8; msk <<= 1) {
                s += __shfl_xor(s, msk, 64);
                q += __shfl_xor(q, msk, 64);
            }
            sm[a][j] = s; sq[a][j] = q;
        }
    if (lrow == 0) {
        #pragma unroll
        for (int a = 0; a < 2; ++a)
            #pragma unroll
            for (int j = 0; j < 4; ++j) {
                int r = a * 16 + kgrp * 4 + j;
                red[wave][r][0] = sm[a][j];
                red[wave][r][1] = sq[a][j];
            }
    }
    __syncthreads();
    #pragma unroll
    for (int a = 0; a < 2; ++a)
        #pragma unroll
        for (int j = 0; j < 4; ++j) {
            const int r = a * 16 + kgrp * 4 + j;
            float S = red[0][r][0] + red[1][r][0] + red[2][r][0] + red[3][r][0];
            float Q = red[0][r][1] + red[1][r][1] + red[2][r][1] + red[3][r][1];
            float mean = S * (1.0f / 512.0f);
            float var  = Q * (1.0f / 512.0f) - mean * mean;
            float rstd = rsqrtf(var + 1e-5f);
            const int m = m0 + a * 16 + kgrp * 4 + j;
            float* orow = out + (size_t)m * 512;
            #pragma unroll
            for (int t = 0; t < 8; ++t) {
                const int n = n0 + t * 16 + lrow;
                float v = (acc[a][t][j] - mean) * rstd * gcol[t] + ecol[t];
                orow[n] = nonsat(v);
            }
        }
}

extern "C" void kernel_launch(void* const* d_in, const int* in_sizes, int n_in,
                              void* d_out, int out_size, void* d_ws, size_t ws_size,
                              hipStream_t stream) {
    const float* x     = (const float*)d_in[0];
    const float* W     = (const float*)d_in[1];
    const float* bias  = (const float*)d_in[2];
    const float* gamma = (const float*)d_in[3];
    const float* beta  = (const float*)d_in[4];
    const float* pe    = (const float*)d_in[5];
    float* out = (float*)d_out;

    const size_t WBF_BYTES = (size_t)KFULL * DMODEL * sizeof(short);   // 1 MB
    const size_t P_BYTES   = (size_t)SEQL * DMODEL * sizeof(float);    // 8 MB

    if (ws_size >= WBF_BYTES + P_BYTES) {
        short* Wbf = (short*)d_ws;
        float* Pv  = (float*)((char*)d_ws + WBF_BYTES);
        cvt_w<<<dim3((DMODEL * KFULL) / (256 * 8)), dim3(256), 0, stream>>>(W, Wbf);
        pe_gemm<<<dim3(SEQL / 32), dim3(256), 0, stream>>>(pe, Wbf, bias, Pv);
        main_fused<<<dim3(MROWS / 32), dim3(256), 0, stream>>>(x, Wbf, Pv, gamma, beta, out);
    } else {
        fallback_fwd<<<dim3(MROWS / 32), dim3(256), 0, stream>>>(x, W, bias, gamma, beta, pe, out);
    }
}